// Round 1
// baseline (1151.474 us; speedup 1.0000x reference)
//
#include <hip/hip_runtime.h>

#define M_NODES 50000
#define E_EDGES 600000
#define EPS_BN 1e-5f

// ---------------- CSR build ----------------
__global__ void k_hist(const int* __restrict__ dst, int* __restrict__ cnt, int n) {
  int e = blockIdx.x * blockDim.x + threadIdx.x;
  if (e < n) atomicAdd(&cnt[dst[e]], 1);
}

__global__ __launch_bounds__(1024) void k_scan(const int* __restrict__ cnt,
                                               int* __restrict__ off, int n) {
  __shared__ int wsum[16];
  __shared__ int carry_s;
  int t = threadIdx.x;
  int lane = t & 63;
  int w = t >> 6;
  if (t == 0) carry_s = 0;
  __syncthreads();
  for (int base = 0; base < n; base += 1024) {
    int i = base + t;
    int v = (i < n) ? cnt[i] : 0;
    int s = v;
    #pragma unroll
    for (int d = 1; d < 64; d <<= 1) {
      int u = __shfl_up(s, d, 64);
      if (lane >= d) s += u;
    }
    if (lane == 63) wsum[w] = s;
    __syncthreads();
    if (t < 16) {
      int xv = wsum[t];
      #pragma unroll
      for (int d = 1; d < 16; d <<= 1) {
        int u = __shfl_up(xv, d, 64);
        if (t >= d) xv += u;
      }
      wsum[t] = xv;
    }
    __syncthreads();
    int waveoff = (w == 0) ? 0 : wsum[w - 1];
    int incl = s + waveoff + carry_s;
    if (i < n) off[i + 1] = incl;
    __syncthreads();
    if (t == 1023) carry_s = incl;
    __syncthreads();
  }
  if (t == 0) off[0] = 0;
}

__global__ void k_fill(const int* __restrict__ src, const int* __restrict__ dst,
                       const int* __restrict__ off, int* __restrict__ fpos,
                       int* __restrict__ csr, int n) {
  int e = blockIdx.x * blockDim.x + threadIdx.x;
  if (e < n) {
    int d = dst[e];
    int p = off[d] + atomicAdd(&fpos[d], 1);
    csr[p] = src[e];
  }
}

// ---------------- mean aggregation: one wave per node ----------------
__global__ __launch_bounds__(256) void k_agg(const float* __restrict__ z,
                                             const int* __restrict__ off,
                                             const int* __restrict__ csr,
                                             float* __restrict__ mean, int M) {
  int node = blockIdx.x * 4 + (threadIdx.x >> 6);
  int lane = threadIdx.x & 63;
  if (node >= M) return;
  int beg = off[node], end = off[node + 1];
  float a0 = 0.f, a1 = 0.f;
  for (int e = beg; e < end; ++e) {
    int s = csr[e];
    float2 v = *(const float2*)(z + (size_t)s * 128 + lane * 2);
    a0 += v.x;
    a1 += v.y;
  }
  int deg = end - beg;
  float inv = 1.0f / (float)(deg > 1 ? deg : 1);
  float2 r;
  r.x = a0 * inv;
  r.y = a1 * inv;
  *(float2*)(mean + (size_t)node * 128 + lane * 2) = r;
}

// ---------------- encoder layer 1: K=7, N=256, relu ----------------
__global__ __launch_bounds__(256) void k_enc1(const float* __restrict__ x,
                                              const float* __restrict__ W1,
                                              const float* __restrict__ b1,
                                              float* __restrict__ h, int M) {
  __shared__ float Ws[256 * 7];
  __shared__ float xs[8 * 7];
  int t = threadIdx.x;
  for (int i = t; i < 256 * 7; i += 256) Ws[i] = W1[i];
  int m0 = blockIdx.x * 8;
  if (t < 56) xs[t] = x[(size_t)m0 * 7 + t];
  __syncthreads();
  float bj = b1[t];
  float wreg[7];
  #pragma unroll
  for (int k = 0; k < 7; ++k) wreg[k] = Ws[t * 7 + k];
  #pragma unroll
  for (int i = 0; i < 8; ++i) {
    float acc = bj;
    #pragma unroll
    for (int k = 0; k < 7; ++k) acc = fmaf(wreg[k], xs[i * 7 + k], acc);
    h[(size_t)(m0 + i) * 256 + t] = fmaxf(acc, 0.f);
  }
}

// ---------------- generic tiled GEMM ----------------
// C[M,N] = [A1 | A2][M,K] @ ([W1 | W2][N,K])^T + bias, split at K1 (K1 % 16 == 0).
// A1 row-stride K1, A2 row-stride K-K1; same for W1/W2. 64x64 tile, 1 wave, 8x8/thread.
__global__ __launch_bounds__(64) void k_gemm(
    const float* __restrict__ A1, const float* __restrict__ A2, int K1,
    const float* __restrict__ W1p, const float* __restrict__ W2p,
    const float* __restrict__ bias, float* __restrict__ C,
    int M, int N, int K, int relu) {
  __shared__ float As[16][64];
  __shared__ float Ws[16][64];
  int t = threadIdx.x;
  int m0 = blockIdx.x * 64;
  int n0 = blockIdx.y * 64;
  int tm = (t >> 3) * 8;
  int tn = (t & 7) * 8;

  float acc[8][8];
  #pragma unroll
  for (int i = 0; i < 8; ++i)
    #pragma unroll
    for (int j = 0; j < 8; ++j) acc[i][j] = 0.f;

  for (int kt = 0; kt < K; kt += 16) {
    const float* A;
    const float* W;
    int kb, lda;
    if (kt < K1) { A = A1; W = W1p; kb = kt; lda = K1; }
    else         { A = A2; W = W2p; kb = kt - K1; lda = K - K1; }

    #pragma unroll
    for (int j = 0; j < 4; ++j) {
      int idx = t + 64 * j;
      int r = idx >> 2;
      int c = (idx & 3) << 2;
      int row = m0 + r;
      float4 v = make_float4(0.f, 0.f, 0.f, 0.f);
      if (row < M) v = *(const float4*)(A + (size_t)row * lda + kb + c);
      As[c + 0][r] = v.x; As[c + 1][r] = v.y; As[c + 2][r] = v.z; As[c + 3][r] = v.w;
    }
    #pragma unroll
    for (int j = 0; j < 4; ++j) {
      int idx = t + 64 * j;
      int r = idx >> 2;
      int c = (idx & 3) << 2;
      float4 v = *(const float4*)(W + (size_t)(n0 + r) * lda + kb + c);
      Ws[c + 0][r] = v.x; Ws[c + 1][r] = v.y; Ws[c + 2][r] = v.z; Ws[c + 3][r] = v.w;
    }
    __syncthreads();
    #pragma unroll
    for (int kk = 0; kk < 16; ++kk) {
      float4 a0 = *(const float4*)&As[kk][tm];
      float4 a1 = *(const float4*)&As[kk][tm + 4];
      float4 b0 = *(const float4*)&Ws[kk][tn];
      float4 b1v = *(const float4*)&Ws[kk][tn + 4];
      float av[8] = {a0.x, a0.y, a0.z, a0.w, a1.x, a1.y, a1.z, a1.w};
      float bv[8] = {b0.x, b0.y, b0.z, b0.w, b1v.x, b1v.y, b1v.z, b1v.w};
      #pragma unroll
      for (int i = 0; i < 8; ++i)
        #pragma unroll
        for (int j = 0; j < 8; ++j)
          acc[i][j] = fmaf(av[i], bv[j], acc[i][j]);
    }
    __syncthreads();
  }

  #pragma unroll
  for (int i = 0; i < 8; ++i) {
    int row = m0 + tm + i;
    if (row >= M) continue;
    float o[8];
    #pragma unroll
    for (int j = 0; j < 8; ++j) {
      float v = acc[i][j] + bias[n0 + tn + j];
      o[j] = relu ? fmaxf(v, 0.f) : v;
    }
    *(float4*)(C + (size_t)row * N + n0 + tn)     = make_float4(o[0], o[1], o[2], o[3]);
    *(float4*)(C + (size_t)row * N + n0 + tn + 4) = make_float4(o[4], o[5], o[6], o[7]);
  }
}

// ---------------- batchnorm ----------------
__global__ __launch_bounds__(256) void k_bn_stats(const float* __restrict__ z,
                                                  float* __restrict__ ssum, int M) {
  int f = threadIdx.x & 127;
  int half = threadIdx.x >> 7;
  int r0 = blockIdx.x * 256;
  int rend = r0 + 256;
  if (rend > M) rend = M;
  float s = 0.f, q = 0.f;
  for (int r = r0 + half; r < rend; r += 2) {
    float v = z[(size_t)r * 128 + f];
    s += v;
    q = fmaf(v, v, q);
  }
  __shared__ float ls[256], lq[256];
  ls[threadIdx.x] = s;
  lq[threadIdx.x] = q;
  __syncthreads();
  if (half == 0) {
    atomicAdd(&ssum[f], ls[f] + ls[f + 128]);
    atomicAdd(&ssum[128 + f], lq[f] + lq[f + 128]);
  }
}

__global__ void k_bn_fin(const float* __restrict__ ssum, const float* __restrict__ g,
                         const float* __restrict__ b, float* __restrict__ sc, int M) {
  int f = threadIdx.x;
  float m = ssum[f] / (float)M;
  float var = ssum[128 + f] / (float)M - m * m;
  float s = g[f] * rsqrtf(var + EPS_BN);
  sc[f] = s;
  sc[128 + f] = b[f] - m * s;
}

__global__ __launch_bounds__(256) void k_bn_apply(float* __restrict__ z,
                                                  const float* __restrict__ sc,
                                                  int total4) {
  int i = blockIdx.x * 256 + threadIdx.x;
  if (i >= total4) return;
  float4 v = ((float4*)z)[i];
  int f = (i & 31) * 4;
  v.x = fmaxf(fmaf(v.x, sc[f + 0], sc[128 + f + 0]), 0.f);
  v.y = fmaxf(fmaf(v.y, sc[f + 1], sc[128 + f + 1]), 0.f);
  v.z = fmaxf(fmaf(v.z, sc[f + 2], sc[128 + f + 2]), 0.f);
  v.w = fmaxf(fmaf(v.w, sc[f + 3], sc[128 + f + 3]), 0.f);
  ((float4*)z)[i] = v;
}

// ---------------- decoder layer 2: N=4, K=256 ----------------
__global__ __launch_bounds__(256) void k_dec2(const float* __restrict__ h,
                                              const float* __restrict__ W,
                                              const float* __restrict__ b,
                                              float* __restrict__ out, int M) {
  __shared__ float Ws[1024];
  int t = threadIdx.x;
  #pragma unroll
  for (int i = t; i < 1024; i += 256) Ws[i] = W[i];
  __syncthreads();
  int node = blockIdx.x * 4 + (t >> 6);
  int lane = t & 63;
  if (node >= M) return;
  const float* hr = h + (size_t)node * 256;
  float a0 = 0.f, a1 = 0.f, a2 = 0.f, a3 = 0.f;
  #pragma unroll
  for (int c = 0; c < 4; ++c) {
    int k = lane + 64 * c;
    float v = hr[k];
    a0 = fmaf(v, Ws[0 * 256 + k], a0);
    a1 = fmaf(v, Ws[1 * 256 + k], a1);
    a2 = fmaf(v, Ws[2 * 256 + k], a2);
    a3 = fmaf(v, Ws[3 * 256 + k], a3);
  }
  #pragma unroll
  for (int o = 32; o > 0; o >>= 1) {
    a0 += __shfl_down(a0, o, 64);
    a1 += __shfl_down(a1, o, 64);
    a2 += __shfl_down(a2, o, 64);
    a3 += __shfl_down(a3, o, 64);
  }
  if (lane == 0) {
    out[(size_t)node * 4 + 0] = a0 + b[0];
    out[(size_t)node * 4 + 1] = a1 + b[1];
    out[(size_t)node * 4 + 2] = a2 + b[2];
    out[(size_t)node * 4 + 3] = a3 + b[3];
  }
}

// ---------------- launch ----------------
extern "C" void kernel_launch(void* const* d_in, const int* in_sizes, int n_in,
                              void* d_out, int out_size, void* d_ws, size_t ws_size,
                              hipStream_t stream) {
  const float* x     = (const float*)d_in[0];
  const int*   ei    = (const int*)d_in[1];
  const float* encW1 = (const float*)d_in[2];
  const float* encb1 = (const float*)d_in[3];
  const float* encW2 = (const float*)d_in[4];
  const float* encb2 = (const float*)d_in[5];
  const float* Wl    = (const float*)d_in[6];
  const float* bl    = (const float*)d_in[7];
  const float* Wr    = (const float*)d_in[8];
  const float* gamma = (const float*)d_in[9];
  const float* beta  = (const float*)d_in[10];
  const float* decW1 = (const float*)d_in[11];
  const float* decb1 = (const float*)d_in[12];
  const float* decW2 = (const float*)d_in[13];
  const float* decb2 = (const float*)d_in[14];
  float* out = (float*)d_out;

  const int M = M_NODES, E = E_EDGES;
  char* p = (char*)d_ws;
  auto take = [&](size_t b) { char* r = p; p += (b + 255) & ~(size_t)255; return r; };
  float* zA   = (float*)take((size_t)M * 128 * 4);
  float* zB   = (float*)take((size_t)M * 128 * 4);
  float* hbuf = (float*)take((size_t)M * 256 * 4);
  int* cnt    = (int*)take((size_t)M * 4);
  int* fpos   = (int*)take((size_t)M * 4);
  int* off    = (int*)take((size_t)(M + 1) * 4);
  int* csr    = (int*)take((size_t)E * 4);
  float* ssum = (float*)take(256 * 4);
  float* sc   = (float*)take(256 * 4);

  const int* srcp = ei;
  const int* dstp = ei + E;

  hipMemsetAsync(cnt, 0, (size_t)M * 4, stream);
  hipMemsetAsync(fpos, 0, (size_t)M * 4, stream);
  k_hist<<<(E + 255) / 256, 256, 0, stream>>>(dstp, cnt, E);
  k_scan<<<1, 1024, 0, stream>>>(cnt, off, M);
  k_fill<<<(E + 255) / 256, 256, 0, stream>>>(srcp, dstp, off, fpos, csr, E);

  // encoder
  k_enc1<<<M / 8, 256, 0, stream>>>(x, encW1, encb1, hbuf, M);
  {
    dim3 g((M + 63) / 64, 2);
    k_gemm<<<g, 64, 0, stream>>>(hbuf, hbuf, 256, encW2, encW2, encb2, zA, M, 128, 256, 0);
  }

  float* cur = zA;
  float* nxt = zB;
  float* meanb = hbuf;  // alias: hbuf unused during conv phase
  for (int i = 0; i < 5; ++i) {
    k_agg<<<M / 4, 256, 0, stream>>>(cur, off, csr, meanb, M);
    dim3 g((M + 63) / 64, 2);
    k_gemm<<<g, 64, 0, stream>>>(meanb, cur, 128,
                                 Wl + (size_t)i * 128 * 128, Wr + (size_t)i * 128 * 128,
                                 bl + (size_t)i * 128, nxt, M, 128, 256, 0);
    if (i < 4) {
      hipMemsetAsync(ssum, 0, 256 * 4, stream);
      k_bn_stats<<<(M + 255) / 256, 256, 0, stream>>>(nxt, ssum, M);
      k_bn_fin<<<1, 128, 0, stream>>>(ssum, gamma + (size_t)i * 128, beta + (size_t)i * 128, sc, M);
      k_bn_apply<<<(M * 32 + 255) / 256, 256, 0, stream>>>(nxt, sc, M * 32);
    }
    float* tswap = cur; cur = nxt; nxt = tswap;
  }

  // decoder
  {
    dim3 g((M + 63) / 64, 4);
    k_gemm<<<g, 64, 0, stream>>>(cur, cur, 128, decW1, decW1, decb1, hbuf, M, 256, 128, 1);
  }
  k_dec2<<<(M + 3) / 4, 256, 0, stream>>>(hbuf, decW2, decb2, out, M);
}

// Round 2
// 732.097 us; speedup vs baseline: 1.5728x; 1.5728x over previous
//
#include <hip/hip_runtime.h>

using u16 = unsigned short;
using u32 = unsigned int;

#define M_NODES 50000
#define E_EDGES 600000
#define EPS_BN 1e-5f

typedef __attribute__((ext_vector_type(8))) short bf16x8;
typedef __attribute__((ext_vector_type(4))) float f32x4;

__device__ __forceinline__ float bf2f(u16 v) {
  union { u32 u; float f; } x; x.u = ((u32)v) << 16; return x.f;
}
__device__ __forceinline__ u16 f2bf(float f) {
  union { float f; u32 u; } x; x.f = f;
  u32 r = x.u + 0x7fffu + ((x.u >> 16) & 1u);
  return (u16)(r >> 16);
}

// ---------------- CSR build ----------------
__global__ void k_hist(const int* __restrict__ dst, int* __restrict__ cnt, int n) {
  int e = blockIdx.x * blockDim.x + threadIdx.x;
  if (e < n) atomicAdd(&cnt[dst[e]], 1);
}

__global__ __launch_bounds__(1024) void k_scan(const int* __restrict__ cnt,
                                               int* __restrict__ off, int n) {
  __shared__ int wsum[16];
  __shared__ int carry_s;
  int t = threadIdx.x;
  int lane = t & 63;
  int w = t >> 6;
  if (t == 0) carry_s = 0;
  __syncthreads();
  for (int base = 0; base < n; base += 1024) {
    int i = base + t;
    int v = (i < n) ? cnt[i] : 0;
    int s = v;
    #pragma unroll
    for (int d = 1; d < 64; d <<= 1) {
      int u = __shfl_up(s, d, 64);
      if (lane >= d) s += u;
    }
    if (lane == 63) wsum[w] = s;
    __syncthreads();
    if (t < 16) {
      int xv = wsum[t];
      #pragma unroll
      for (int d = 1; d < 16; d <<= 1) {
        int u = __shfl_up(xv, d, 64);
        if (t >= d) xv += u;
      }
      wsum[t] = xv;
    }
    __syncthreads();
    int waveoff = (w == 0) ? 0 : wsum[w - 1];
    int incl = s + waveoff + carry_s;
    if (i < n) off[i + 1] = incl;
    __syncthreads();
    if (t == 1023) carry_s = incl;
    __syncthreads();
  }
  if (t == 0) off[0] = 0;
}

__global__ void k_fill(const int* __restrict__ src, const int* __restrict__ dst,
                       const int* __restrict__ off, int* __restrict__ fpos,
                       int* __restrict__ csr, int n) {
  int e = blockIdx.x * blockDim.x + threadIdx.x;
  if (e < n) {
    int d = dst[e];
    int p = off[d] + atomicAdd(&fpos[d], 1);
    csr[p] = src[e];
  }
}

// ---------------- weight prep: fp32 -> bf16 packed ----------------
// Bpack layout (ushort): [0,32768) encW2 [128][256]
//                        [32768 + i*32768) conv i: B[n][k] = k<128 ? Wl[i][n][k] : Wr[i][n][k-128]
//                        [196608, 229376) decW1 [256][128]
__global__ __launch_bounds__(256) void k_prep(const float* __restrict__ encW2,
                                              const float* __restrict__ Wl,
                                              const float* __restrict__ Wr,
                                              const float* __restrict__ decW1,
                                              u16* __restrict__ Bp) {
  int e = blockIdx.x * 256 + threadIdx.x;
  float v;
  if (e < 32768) {
    v = encW2[e];
  } else if (e < 196608) {
    int r = e - 32768;
    int i = r >> 15;
    int rr = r & 32767;
    int n = rr >> 8;
    int k = rr & 255;
    v = (k < 128) ? Wl[i * 16384 + n * 128 + k] : Wr[i * 16384 + n * 128 + (k - 128)];
  } else {
    v = decW1[e - 196608];
  }
  Bp[e] = f2bf(v);
}

// ---------------- mean aggregation (bf16): one wave per node ----------------
__global__ __launch_bounds__(256) void k_agg(const u16* __restrict__ z,
                                             const int* __restrict__ off,
                                             const int* __restrict__ csr,
                                             u16* __restrict__ mean, int M) {
  int node = blockIdx.x * 4 + (threadIdx.x >> 6);
  int lane = threadIdx.x & 63;
  if (node >= M) return;
  int beg = off[node], end = off[node + 1];
  float a0 = 0.f, a1 = 0.f;
  for (int e = beg; e < end; ++e) {
    int s = csr[e];
    u32 v = *(const u32*)(z + (size_t)s * 128 + lane * 2);
    union { u32 u; float f; } lo, hi;
    lo.u = v << 16;
    hi.u = v & 0xffff0000u;
    a0 += lo.f;
    a1 += hi.f;
  }
  int deg = end - beg;
  float inv = 1.0f / (float)(deg > 1 ? deg : 1);
  u32 r = (u32)f2bf(a0 * inv) | ((u32)f2bf(a1 * inv) << 16);
  *(u32*)(mean + (size_t)node * 128 + lane * 2) = r;
}

// ---------------- encoder layer 1: K=7, N=256, relu, bf16 out ----------------
__global__ __launch_bounds__(256) void k_enc1(const float* __restrict__ x,
                                              const float* __restrict__ W1,
                                              const float* __restrict__ b1,
                                              u16* __restrict__ h, int M) {
  __shared__ float Ws[256 * 7];
  __shared__ float xs[8 * 7];
  int t = threadIdx.x;
  for (int i = t; i < 256 * 7; i += 256) Ws[i] = W1[i];
  int m0 = blockIdx.x * 8;
  if (t < 56) xs[t] = x[(size_t)m0 * 7 + t];
  __syncthreads();
  float bj = b1[t];
  float wreg[7];
  #pragma unroll
  for (int k = 0; k < 7; ++k) wreg[k] = Ws[t * 7 + k];
  #pragma unroll
  for (int i = 0; i < 8; ++i) {
    float acc = bj;
    #pragma unroll
    for (int k = 0; k < 7; ++k) acc = fmaf(wreg[k], xs[i * 7 + k], acc);
    h[(size_t)(m0 + i) * 256 + t] = f2bf(fmaxf(acc, 0.f));
  }
}

// ---------------- bf16 MFMA GEMM ----------------
// C[M, N] (bf16, ldc) = A[M, K] @ Bp[N, K]^T + bias.  K = KSTEPS*32.
// A columns [0, K/2) come from A1 (stride strideA), [K/2, K) from A2 (stride strideA).
// 128x128 tile per block (4 waves, 2x2), BK=32, double-buffered global_load_lds.
#define GLOAD_LDS16(g, l)                                                        \
  __builtin_amdgcn_global_load_lds((const __attribute__((address_space(1))) void*)(g), \
                                   (__attribute__((address_space(3))) void*)(l), 16, 0, 0)

template <int KSTEPS>
__global__ __launch_bounds__(256) void k_mfma_gemm(
    const u16* __restrict__ A1, const u16* __restrict__ A2, int strideA,
    const u16* __restrict__ Bp, const float* __restrict__ bias,
    u16* __restrict__ C, int ldc, int M, int relu) {
  constexpr int KHALF = KSTEPS / 2;
  __shared__ __align__(16) u16 As[2][4096];
  __shared__ __align__(16) u16 Bs[2][4096];
  int t = threadIdx.x;
  int lane = t & 63;
  int w = t >> 6;
  int m0 = blockIdx.x * 128;
  int n0 = blockIdx.y * 128;

  f32x4 acc[4][4] = {};

  auto stage = [&](int kt, int b) {
    #pragma unroll
    for (int j = 0; j < 2; ++j) {
      int s = (w * 2 + j) * 64 + lane;   // 0..511: 16B slot index
      int row = s >> 2;                  // 0..127
      int cc = (s & 3) ^ ((row >> 1) & 3);  // pre-swizzled source chunk
      // A tile
      {
        int rg = m0 + row;
        rg = rg < M ? rg : M - 1;
        const u16* src = (kt < KHALF ? A1 : A2) + (size_t)rg * strideA + (kt % KHALF) * 32 + cc * 8;
        GLOAD_LDS16(src, &As[b][(w * 2 + j) * 512]);
      }
      // B tile
      {
        const u16* src = Bp + (size_t)(n0 + row) * (KSTEPS * 32) + kt * 32 + cc * 8;
        GLOAD_LDS16(src, &Bs[b][(w * 2 + j) * 512]);
      }
    }
  };

  stage(0, 0);
  #pragma unroll
  for (int kt = 0; kt < KSTEPS; ++kt) {
    const int b = kt & 1;
    if (kt + 1 < KSTEPS) {
      stage(kt + 1, (kt + 1) & 1);
      asm volatile("s_waitcnt vmcnt(4)" ::: "memory");
    } else {
      asm volatile("s_waitcnt vmcnt(0)" ::: "memory");
    }
    __builtin_amdgcn_s_barrier();
    asm volatile("" ::: "memory");

    bf16x8 af[4], bfr[4];
    int c16 = lane >> 4;
    #pragma unroll
    for (int mf = 0; mf < 4; ++mf) {
      int row = (w & 1) * 64 + mf * 16 + (lane & 15);
      int cs = c16 ^ ((row >> 1) & 3);
      af[mf] = *(const bf16x8*)&As[b][row * 32 + cs * 8];
    }
    #pragma unroll
    for (int nf = 0; nf < 4; ++nf) {
      int row = (w >> 1) * 64 + nf * 16 + (lane & 15);
      int cs = c16 ^ ((row >> 1) & 3);
      bfr[nf] = *(const bf16x8*)&Bs[b][row * 32 + cs * 8];
    }
    #pragma unroll
    for (int mf = 0; mf < 4; ++mf)
      #pragma unroll
      for (int nf = 0; nf < 4; ++nf)
        acc[mf][nf] = __builtin_amdgcn_mfma_f32_16x16x32_bf16(af[mf], bfr[nf], acc[mf][nf], 0, 0, 0);

    asm volatile("s_waitcnt lgkmcnt(0)" ::: "memory");
    __builtin_amdgcn_sched_barrier(0);
    __builtin_amdgcn_s_barrier();
    asm volatile("" ::: "memory");
  }

  // epilogue: D row = (lane>>4)*4 + j, col = lane&15 within each 16x16 frag
  int c16 = lane >> 4;
  #pragma unroll
  for (int mf = 0; mf < 4; ++mf) {
    #pragma unroll
    for (int j = 0; j < 4; ++j) {
      int rl = (w & 1) * 64 + mf * 16 + c16 * 4 + j;
      int rg = m0 + rl;
      if (rg < M) {
        #pragma unroll
        for (int nf = 0; nf < 4; ++nf) {
          int cl = (w >> 1) * 64 + nf * 16 + (lane & 15);
          float v = acc[mf][nf][j] + bias[n0 + cl];
          if (relu) v = fmaxf(v, 0.f);
          C[(size_t)rg * ldc + n0 + cl] = f2bf(v);
        }
      }
    }
  }
}

// ---------------- batchnorm (bf16 data, fp32 stats) ----------------
__global__ __launch_bounds__(256) void k_bn_stats(const u16* __restrict__ z,
                                                  float* __restrict__ ssum, int M) {
  int f = threadIdx.x & 127;
  int half = threadIdx.x >> 7;
  int r0 = blockIdx.x * 256;
  int rend = r0 + 256;
  if (rend > M) rend = M;
  float s = 0.f, q = 0.f;
  for (int r = r0 + half; r < rend; r += 2) {
    float v = bf2f(z[(size_t)r * 128 + f]);
    s += v;
    q = fmaf(v, v, q);
  }
  __shared__ float ls[256], lq[256];
  ls[threadIdx.x] = s;
  lq[threadIdx.x] = q;
  __syncthreads();
  if (half == 0) {
    atomicAdd(&ssum[f], ls[f] + ls[f + 128]);
    atomicAdd(&ssum[128 + f], lq[f] + lq[f + 128]);
  }
}

__global__ void k_bn_fin(const float* __restrict__ ssum, const float* __restrict__ g,
                         const float* __restrict__ b, float* __restrict__ sc, int M) {
  int f = threadIdx.x;
  float m = ssum[f] / (float)M;
  float var = ssum[128 + f] / (float)M - m * m;
  float s = g[f] * rsqrtf(var + EPS_BN);
  sc[f] = s;
  sc[128 + f] = b[f] - m * s;
}

__global__ __launch_bounds__(256) void k_bn_apply(u16* __restrict__ z,
                                                  const float* __restrict__ sc,
                                                  int total4) {
  int i = blockIdx.x * 256 + threadIdx.x;
  if (i >= total4) return;
  ushort4 v = ((ushort4*)z)[i];
  int f = (i & 31) * 4;
  float o0 = fmaxf(fmaf(bf2f(v.x), sc[f + 0], sc[128 + f + 0]), 0.f);
  float o1 = fmaxf(fmaf(bf2f(v.y), sc[f + 1], sc[128 + f + 1]), 0.f);
  float o2 = fmaxf(fmaf(bf2f(v.z), sc[f + 2], sc[128 + f + 2]), 0.f);
  float o3 = fmaxf(fmaf(bf2f(v.w), sc[f + 3], sc[128 + f + 3]), 0.f);
  ushort4 r;
  r.x = f2bf(o0); r.y = f2bf(o1); r.z = f2bf(o2); r.w = f2bf(o3);
  ((ushort4*)z)[i] = r;
}

// ---------------- decoder layer 2: N=4, K=256, bf16 in ----------------
__global__ __launch_bounds__(256) void k_dec2(const u16* __restrict__ h,
                                              const float* __restrict__ W,
                                              const float* __restrict__ b,
                                              float* __restrict__ out, int M) {
  __shared__ float Ws[1024];
  int t = threadIdx.x;
  for (int i = t; i < 1024; i += 256) Ws[i] = W[i];
  __syncthreads();
  int node = blockIdx.x * 4 + (t >> 6);
  int lane = t & 63;
  if (node >= M) return;
  const u16* hr = h + (size_t)node * 256;
  ushort4 v = *(const ushort4*)(hr + lane * 4);
  float f0 = bf2f(v.x), f1 = bf2f(v.y), f2v = bf2f(v.z), f3 = bf2f(v.w);
  float a[4];
  #pragma unroll
  for (int o = 0; o < 4; ++o) {
    const float* wr = Ws + o * 256 + lane * 4;
    a[o] = f0 * wr[0] + f1 * wr[1] + f2v * wr[2] + f3 * wr[3];
  }
  #pragma unroll
  for (int off = 32; off > 0; off >>= 1) {
    #pragma unroll
    for (int o = 0; o < 4; ++o) a[o] += __shfl_down(a[o], off, 64);
  }
  if (lane == 0) {
    #pragma unroll
    for (int o = 0; o < 4; ++o) out[(size_t)node * 4 + o] = a[o] + b[o];
  }
}

// ---------------- launch ----------------
extern "C" void kernel_launch(void* const* d_in, const int* in_sizes, int n_in,
                              void* d_out, int out_size, void* d_ws, size_t ws_size,
                              hipStream_t stream) {
  const float* x     = (const float*)d_in[0];
  const int*   ei    = (const int*)d_in[1];
  const float* encW1 = (const float*)d_in[2];
  const float* encb1 = (const float*)d_in[3];
  const float* encW2 = (const float*)d_in[4];
  const float* encb2 = (const float*)d_in[5];
  const float* Wl    = (const float*)d_in[6];
  const float* bl    = (const float*)d_in[7];
  const float* Wr    = (const float*)d_in[8];
  const float* gamma = (const float*)d_in[9];
  const float* beta  = (const float*)d_in[10];
  const float* decW1 = (const float*)d_in[11];
  const float* decb1 = (const float*)d_in[12];
  const float* decW2 = (const float*)d_in[13];
  const float* decb2 = (const float*)d_in[14];
  float* out = (float*)d_out;

  const int M = M_NODES, E = E_EDGES;
  char* p = (char*)d_ws;
  auto take = [&](size_t b) { char* r = p; p += (b + 255) & ~(size_t)255; return r; };
  u16* zA    = (u16*)take((size_t)M * 128 * 2);
  u16* zB    = (u16*)take((size_t)M * 128 * 2);
  u16* mean  = (u16*)take((size_t)M * 128 * 2);
  u16* hbuf  = (u16*)take((size_t)M * 256 * 2);
  u16* Bpack = (u16*)take((size_t)229376 * 2);
  int* cnt   = (int*)take((size_t)M * 4);
  int* fpos  = (int*)take((size_t)M * 4);
  int* off   = (int*)take((size_t)(M + 1) * 4);
  int* csr   = (int*)take((size_t)E * 4);
  float* ssum = (float*)take(256 * 4);
  float* sc   = (float*)take(256 * 4);

  const int* srcp = ei;
  const int* dstp = ei + E;

  k_prep<<<896, 256, 0, stream>>>(encW2, Wl, Wr, decW1, Bpack);

  hipMemsetAsync(cnt, 0, (size_t)M * 4, stream);
  hipMemsetAsync(fpos, 0, (size_t)M * 4, stream);
  k_hist<<<(E + 255) / 256, 256, 0, stream>>>(dstp, cnt, E);
  k_scan<<<1, 1024, 0, stream>>>(cnt, off, M);
  k_fill<<<(E + 255) / 256, 256, 0, stream>>>(srcp, dstp, off, fpos, csr, E);

  const int GX = (M + 127) / 128;

  // encoder
  k_enc1<<<M / 8, 256, 0, stream>>>(x, encW1, encb1, hbuf, M);
  k_mfma_gemm<8><<<dim3(GX, 1), 256, 0, stream>>>(hbuf, hbuf + 128, 256, Bpack, encb2,
                                                  zA, 128, M, 0);

  u16* cur = zA;
  u16* nxt = zB;
  for (int i = 0; i < 5; ++i) {
    k_agg<<<M / 4, 256, 0, stream>>>(cur, off, csr, mean, M);
    k_mfma_gemm<8><<<dim3(GX, 1), 256, 0, stream>>>(mean, cur, 128,
                                                    Bpack + 32768 + i * 32768,
                                                    bl + (size_t)i * 128, nxt, 128, M, 0);
    if (i < 4) {
      hipMemsetAsync(ssum, 0, 256 * 4, stream);
      k_bn_stats<<<(M + 255) / 256, 256, 0, stream>>>(nxt, ssum, M);
      k_bn_fin<<<1, 128, 0, stream>>>(ssum, gamma + (size_t)i * 128, beta + (size_t)i * 128, sc, M);
      k_bn_apply<<<(M * 32 + 255) / 256, 256, 0, stream>>>(nxt, sc, M * 32);
    }
    u16* tswap = cur; cur = nxt; nxt = tswap;
  }

  // decoder
  k_mfma_gemm<4><<<dim3(GX, 2), 256, 0, stream>>>(cur, cur + 64, 128, Bpack + 196608,
                                                  decb1, hbuf, 256, M, 1);
  k_dec2<<<(M + 3) / 4, 256, 0, stream>>>(hbuf, decW2, decb2, out, M);
}

// Round 3
// 404.321 us; speedup vs baseline: 2.8479x; 1.8107x over previous
//
#include <hip/hip_runtime.h>

using u16 = unsigned short;
using u32 = unsigned int;

#define M_NODES 50000
#define E_EDGES 600000
#define EPS_BN 1e-5f
#define BKT 48

typedef __attribute__((ext_vector_type(8))) short bf16x8;
typedef __attribute__((ext_vector_type(4))) float f32x4;

__device__ __forceinline__ float bf2f(u16 v) {
  union { u32 u; float f; } x; x.u = ((u32)v) << 16; return x.f;
}
__device__ __forceinline__ float lo16f(u32 v) {
  union { u32 u; float f; } x; x.u = v << 16; return x.f;
}
__device__ __forceinline__ float hi16f(u32 v) {
  union { u32 u; float f; } x; x.u = v & 0xffff0000u; return x.f;
}
__device__ __forceinline__ u16 f2bf(float f) {
  union { float f; u32 u; } x; x.f = f;
  u32 r = x.u + 0x7fffu + ((x.u >> 16) & 1u);
  return (u16)(r >> 16);
}

// ---------------- bucket build (replaces hist+scan+fill) ----------------
__global__ void k_place(const int* __restrict__ src, const int* __restrict__ dst,
                        int* __restrict__ cnt, int* __restrict__ bucket, int n) {
  int e = blockIdx.x * blockDim.x + threadIdx.x;
  if (e < n) {
    int d = dst[e];
    int p = atomicAdd(&cnt[d], 1);
    if (p < BKT) bucket[d * BKT + p] = src[e];
  }
}

// ---------------- weight prep: fp32 -> bf16 packed ----------------
// Bpack layout (ushort): [0,32768) encW2 [128][256]
//                        [32768 + i*32768) conv i: B[n][k] = k<128 ? Wl : Wr
//                        [196608, 229376) decW1 [256][128]
__global__ __launch_bounds__(256) void k_prep(const float* __restrict__ encW2,
                                              const float* __restrict__ Wl,
                                              const float* __restrict__ Wr,
                                              const float* __restrict__ decW1,
                                              u16* __restrict__ Bp) {
  int e = blockIdx.x * 256 + threadIdx.x;
  float v;
  if (e < 32768) {
    v = encW2[e];
  } else if (e < 196608) {
    int r = e - 32768;
    int i = r >> 15;
    int rr = r & 32767;
    int n = rr >> 8;
    int k = rr & 255;
    v = (k < 128) ? Wl[i * 16384 + n * 128 + k] : Wr[i * 16384 + n * 128 + (k - 128)];
  } else {
    v = decW1[e - 196608];
  }
  Bp[e] = f2bf(v);
}

// ---------------- mean aggregation: wave/node, 4 edge-slots x 16 lanes ----------------
__global__ __launch_bounds__(256) void k_agg(const u16* __restrict__ z,
                                             const int* __restrict__ cnt,
                                             const int* __restrict__ bucket,
                                             u16* __restrict__ mean, int M) {
  int node = blockIdx.x * 4 + (threadIdx.x >> 6);
  int lane = threadIdx.x & 63;
  if (node >= M) return;
  int slot = lane >> 4;
  int fc = lane & 15;
  int deg = cnt[node];
  int nd = deg < BKT ? deg : BKT;
  const int* bk = bucket + (size_t)node * BKT;
  float a[8] = {};
  for (int j = slot; j < nd; j += 4) {
    int s = bk[j];
    uint4 v = *(const uint4*)(z + (size_t)s * 128 + fc * 8);
    a[0] += lo16f(v.x); a[1] += hi16f(v.x);
    a[2] += lo16f(v.y); a[3] += hi16f(v.y);
    a[4] += lo16f(v.z); a[5] += hi16f(v.z);
    a[6] += lo16f(v.w); a[7] += hi16f(v.w);
  }
  #pragma unroll
  for (int i = 0; i < 8; ++i) {
    a[i] += __shfl_xor(a[i], 16, 64);
    a[i] += __shfl_xor(a[i], 32, 64);
  }
  if (slot == 0) {
    float inv = 1.0f / (float)(deg > 1 ? deg : 1);
    uint4 r;
    r.x = (u32)f2bf(a[0] * inv) | ((u32)f2bf(a[1] * inv) << 16);
    r.y = (u32)f2bf(a[2] * inv) | ((u32)f2bf(a[3] * inv) << 16);
    r.z = (u32)f2bf(a[4] * inv) | ((u32)f2bf(a[5] * inv) << 16);
    r.w = (u32)f2bf(a[6] * inv) | ((u32)f2bf(a[7] * inv) << 16);
    *(uint4*)(mean + (size_t)node * 128 + fc * 8) = r;
  }
}

// ---------------- encoder layer 1: K=7, N=256, relu, bf16 out ----------------
__global__ __launch_bounds__(256) void k_enc1(const float* __restrict__ x,
                                              const float* __restrict__ W1,
                                              const float* __restrict__ b1,
                                              u16* __restrict__ h, int M) {
  __shared__ float Ws[256 * 7];
  __shared__ float xs[8 * 7];
  int t = threadIdx.x;
  for (int i = t; i < 256 * 7; i += 256) Ws[i] = W1[i];
  int m0 = blockIdx.x * 8;
  if (t < 56) xs[t] = x[(size_t)m0 * 7 + t];
  __syncthreads();
  float bj = b1[t];
  float wreg[7];
  #pragma unroll
  for (int k = 0; k < 7; ++k) wreg[k] = Ws[t * 7 + k];
  #pragma unroll
  for (int i = 0; i < 8; ++i) {
    float acc = bj;
    #pragma unroll
    for (int k = 0; k < 7; ++k) acc = fmaf(wreg[k], xs[i * 7 + k], acc);
    h[(size_t)(m0 + i) * 256 + t] = f2bf(fmaxf(acc, 0.f));
  }
}

// ---------------- bf16 MFMA GEMM, BM=64 x BN=128, optional fused BN stats ----------------
#define GLOAD_LDS16(g, l)                                                        \
  __builtin_amdgcn_global_load_lds((const __attribute__((address_space(1))) void*)(g), \
                                   (__attribute__((address_space(3))) void*)(l), 16, 0, 0)

template <int KSTEPS, int DO_STATS>
__global__ __launch_bounds__(256) void k_mfma_gemm(
    const u16* __restrict__ A1, const u16* __restrict__ A2, int strideA,
    const u16* __restrict__ Bp, const float* __restrict__ bias,
    u16* __restrict__ C, int ldc, int M, int relu, float* __restrict__ ssum) {
  constexpr int KHALF = KSTEPS / 2;
  __shared__ __align__(16) u16 As[2][2048];   // 64 rows x 32
  __shared__ __align__(16) u16 Bs[2][4096];   // 128 rows x 32
  __shared__ float bnbuf[256];
  int t = threadIdx.x;
  int lane = t & 63;
  int w = t >> 6;
  int m0 = blockIdx.x * 64;
  int n0 = blockIdx.y * 128;
  if (DO_STATS) bnbuf[t] = 0.f;

  f32x4 acc[2][4] = {};

  auto stage = [&](int kt, int b) {
    // A tile: wave w covers rows w*16 .. w*16+15
    {
      int s = w * 64 + lane;
      int row = s >> 2;
      int cc = (s & 3) ^ ((row >> 1) & 3);
      int rg = m0 + row;
      rg = rg < M ? rg : M - 1;
      const u16* src = (kt < KHALF ? A1 : A2) + (size_t)rg * strideA + (kt % KHALF) * 32 + cc * 8;
      GLOAD_LDS16(src, &As[b][w * 512]);
    }
    // B tile: 2 issues per wave
    #pragma unroll
    for (int j = 0; j < 2; ++j) {
      int s = (w * 2 + j) * 64 + lane;
      int row = s >> 2;
      int cc = (s & 3) ^ ((row >> 1) & 3);
      const u16* src = Bp + (size_t)(n0 + row) * (KSTEPS * 32) + kt * 32 + cc * 8;
      GLOAD_LDS16(src, &Bs[b][(w * 2 + j) * 512]);
    }
  };

  stage(0, 0);
  #pragma unroll
  for (int kt = 0; kt < KSTEPS; ++kt) {
    const int b = kt & 1;
    if (kt + 1 < KSTEPS) {
      stage(kt + 1, (kt + 1) & 1);
      asm volatile("s_waitcnt vmcnt(3)" ::: "memory");
    } else {
      asm volatile("s_waitcnt vmcnt(0)" ::: "memory");
    }
    __builtin_amdgcn_s_barrier();
    asm volatile("" ::: "memory");

    bf16x8 af[2], bfr[4];
    int c16 = lane >> 4;
    #pragma unroll
    for (int mf = 0; mf < 2; ++mf) {
      int row = (w & 1) * 32 + mf * 16 + (lane & 15);
      int cs = c16 ^ ((row >> 1) & 3);
      af[mf] = *(const bf16x8*)&As[b][row * 32 + cs * 8];
    }
    #pragma unroll
    for (int nf = 0; nf < 4; ++nf) {
      int row = (w >> 1) * 64 + nf * 16 + (lane & 15);
      int cs = c16 ^ ((row >> 1) & 3);
      bfr[nf] = *(const bf16x8*)&Bs[b][row * 32 + cs * 8];
    }
    #pragma unroll
    for (int mf = 0; mf < 2; ++mf)
      #pragma unroll
      for (int nf = 0; nf < 4; ++nf)
        acc[mf][nf] = __builtin_amdgcn_mfma_f32_16x16x32_bf16(af[mf], bfr[nf], acc[mf][nf], 0, 0, 0);

    asm volatile("s_waitcnt lgkmcnt(0)" ::: "memory");
    __builtin_amdgcn_sched_barrier(0);
    __builtin_amdgcn_s_barrier();
    asm volatile("" ::: "memory");
  }

  // epilogue: frag D row = c16*4 + j, col = lane&15
  int c16 = lane >> 4;
  float cs_[4] = {}, cq_[4] = {};
  float breg[4];
  #pragma unroll
  for (int nf = 0; nf < 4; ++nf)
    breg[nf] = bias[n0 + (w >> 1) * 64 + nf * 16 + (lane & 15)];
  #pragma unroll
  for (int mf = 0; mf < 2; ++mf) {
    #pragma unroll
    for (int j = 0; j < 4; ++j) {
      int rl = (w & 1) * 32 + mf * 16 + c16 * 4 + j;
      int rg = m0 + rl;
      if (rg < M) {
        #pragma unroll
        for (int nf = 0; nf < 4; ++nf) {
          int cl = (w >> 1) * 64 + nf * 16 + (lane & 15);
          float v = acc[mf][nf][j] + breg[nf];
          if (relu) v = fmaxf(v, 0.f);
          C[(size_t)rg * ldc + n0 + cl] = f2bf(v);
          if (DO_STATS) { cs_[nf] += v; cq_[nf] = fmaf(v, v, cq_[nf]); }
        }
      }
    }
  }

  if (DO_STATS) {
    #pragma unroll
    for (int nf = 0; nf < 4; ++nf) {
      float s = cs_[nf], q = cq_[nf];
      s += __shfl_xor(s, 16, 64); s += __shfl_xor(s, 32, 64);
      q += __shfl_xor(q, 16, 64); q += __shfl_xor(q, 32, 64);
      if (c16 == 0) {
        int cl = (w >> 1) * 64 + nf * 16 + (lane & 15);
        atomicAdd(&bnbuf[cl], s);
        atomicAdd(&bnbuf[128 + cl], q);
      }
    }
    __syncthreads();
    atomicAdd(&ssum[t], bnbuf[t]);
  }
}

// ---------------- batchnorm finalize + apply ----------------
__global__ void k_bn_fin(const float* __restrict__ ssum, const float* __restrict__ g,
                         const float* __restrict__ b, float* __restrict__ sc, int M) {
  int f = threadIdx.x;
  float m = ssum[f] / (float)M;
  float var = ssum[128 + f] / (float)M - m * m;
  float s = g[f] * rsqrtf(var + EPS_BN);
  sc[f] = s;
  sc[128 + f] = b[f] - m * s;
}

__global__ __launch_bounds__(256) void k_bn_apply(u16* __restrict__ z,
                                                  const float* __restrict__ sc,
                                                  int total4) {
  int i = blockIdx.x * 256 + threadIdx.x;
  if (i >= total4) return;
  ushort4 v = ((ushort4*)z)[i];
  int f = (i & 31) * 4;
  float o0 = fmaxf(fmaf(bf2f(v.x), sc[f + 0], sc[128 + f + 0]), 0.f);
  float o1 = fmaxf(fmaf(bf2f(v.y), sc[f + 1], sc[128 + f + 1]), 0.f);
  float o2 = fmaxf(fmaf(bf2f(v.z), sc[f + 2], sc[128 + f + 2]), 0.f);
  float o3 = fmaxf(fmaf(bf2f(v.w), sc[f + 3], sc[128 + f + 3]), 0.f);
  ushort4 r;
  r.x = f2bf(o0); r.y = f2bf(o1); r.z = f2bf(o2); r.w = f2bf(o3);
  ((ushort4*)z)[i] = r;
}

// ---------------- decoder layer 2: N=4, K=256, bf16 in ----------------
__global__ __launch_bounds__(256) void k_dec2(const u16* __restrict__ h,
                                              const float* __restrict__ W,
                                              const float* __restrict__ b,
                                              float* __restrict__ out, int M) {
  __shared__ float Ws[1024];
  int t = threadIdx.x;
  for (int i = t; i < 1024; i += 256) Ws[i] = W[i];
  __syncthreads();
  int node = blockIdx.x * 4 + (t >> 6);
  int lane = t & 63;
  if (node >= M) return;
  const u16* hr = h + (size_t)node * 256;
  ushort4 v = *(const ushort4*)(hr + lane * 4);
  float f0 = bf2f(v.x), f1 = bf2f(v.y), f2v = bf2f(v.z), f3 = bf2f(v.w);
  float a[4];
  #pragma unroll
  for (int o = 0; o < 4; ++o) {
    const float* wr = Ws + o * 256 + lane * 4;
    a[o] = f0 * wr[0] + f1 * wr[1] + f2v * wr[2] + f3 * wr[3];
  }
  #pragma unroll
  for (int off = 32; off > 0; off >>= 1) {
    #pragma unroll
    for (int o = 0; o < 4; ++o) a[o] += __shfl_down(a[o], off, 64);
  }
  if (lane == 0) {
    #pragma unroll
    for (int o = 0; o < 4; ++o) out[(size_t)node * 4 + o] = a[o] + b[o];
  }
}

// ---------------- launch ----------------
extern "C" void kernel_launch(void* const* d_in, const int* in_sizes, int n_in,
                              void* d_out, int out_size, void* d_ws, size_t ws_size,
                              hipStream_t stream) {
  const float* x     = (const float*)d_in[0];
  const int*   ei    = (const int*)d_in[1];
  const float* encW1 = (const float*)d_in[2];
  const float* encb1 = (const float*)d_in[3];
  const float* encW2 = (const float*)d_in[4];
  const float* encb2 = (const float*)d_in[5];
  const float* Wl    = (const float*)d_in[6];
  const float* bl    = (const float*)d_in[7];
  const float* Wr    = (const float*)d_in[8];
  const float* gamma = (const float*)d_in[9];
  const float* beta  = (const float*)d_in[10];
  const float* decW1 = (const float*)d_in[11];
  const float* decb1 = (const float*)d_in[12];
  const float* decW2 = (const float*)d_in[13];
  const float* decb2 = (const float*)d_in[14];
  float* out = (float*)d_out;

  const int M = M_NODES, E = E_EDGES;
  char* p = (char*)d_ws;
  auto take = [&](size_t b) { char* r = p; p += (b + 255) & ~(size_t)255; return r; };
  u16* zA     = (u16*)take((size_t)M * 128 * 2);
  u16* zB     = (u16*)take((size_t)M * 128 * 2);
  u16* mean   = (u16*)take((size_t)M * 128 * 2);
  u16* hbuf   = (u16*)take((size_t)M * 256 * 2);
  u16* Bpack  = (u16*)take((size_t)229376 * 2);
  int* cnt    = (int*)take((size_t)M * 4);
  int* bucket = (int*)take((size_t)M * BKT * 4);
  float* ssum = (float*)take(256 * 4);
  float* sc   = (float*)take(256 * 4);

  const int* srcp = ei;
  const int* dstp = ei + E;

  k_prep<<<896, 256, 0, stream>>>(encW2, Wl, Wr, decW1, Bpack);
  hipMemsetAsync(cnt, 0, (size_t)M * 4, stream);
  k_place<<<(E + 255) / 256, 256, 0, stream>>>(srcp, dstp, cnt, bucket, E);

  const int GX = (M + 63) / 64;

  // encoder
  k_enc1<<<M / 8, 256, 0, stream>>>(x, encW1, encb1, hbuf, M);
  k_mfma_gemm<8, 0><<<dim3(GX, 1), 256, 0, stream>>>(hbuf, hbuf + 128, 256, Bpack, encb2,
                                                     zA, 128, M, 0, nullptr);

  u16* cur = zA;
  u16* nxt = zB;
  for (int i = 0; i < 5; ++i) {
    k_agg<<<M / 4, 256, 0, stream>>>(cur, cnt, bucket, mean, M);
    if (i < 4) {
      hipMemsetAsync(ssum, 0, 256 * 4, stream);
      k_mfma_gemm<8, 1><<<dim3(GX, 1), 256, 0, stream>>>(mean, cur, 128,
                                                         Bpack + 32768 + i * 32768,
                                                         bl + (size_t)i * 128, nxt, 128, M, 0, ssum);
      k_bn_fin<<<1, 128, 0, stream>>>(ssum, gamma + (size_t)i * 128, beta + (size_t)i * 128, sc, M);
      k_bn_apply<<<(M * 32 + 255) / 256, 256, 0, stream>>>(nxt, sc, M * 32);
    } else {
      k_mfma_gemm<8, 0><<<dim3(GX, 1), 256, 0, stream>>>(mean, cur, 128,
                                                         Bpack + 32768 + i * 32768,
                                                         bl + (size_t)i * 128, nxt, 128, M, 0, nullptr);
    }
    u16* tswap = cur; cur = nxt; nxt = tswap;
  }

  // decoder
  k_mfma_gemm<4, 0><<<dim3(GX, 2), 256, 0, stream>>>(cur, cur + 64, 128, Bpack + 196608,
                                                     decb1, hbuf, 256, M, 1, nullptr);
  k_dec2<<<(M + 3) / 4, 256, 0, stream>>>(hbuf, decW2, decb2, out, M);
}